// Round 2
// baseline (9384.882 us; speedup 1.0000x reference)
//
#include <hip/hip_runtime.h>
#include <hip/hip_fp16.h>

#define B_   128
#define L_   1024
#define DIN  64
#define H_   512
#define DOUT 64

typedef _Float16 half8 __attribute__((ext_vector_type(8)));
typedef float    f32x4 __attribute__((ext_vector_type(4)));

#define FSTR 16           // flag stride in ints (64B)
#define SLEEP_CAP 16384   // safety: converts a protocol bug into wrong-answer, not a hang

// ---------------- flag init (re-run every launch -> graph-replay safe) ----------------
__global__ void k_init_flags(int* flags) {
    int i = threadIdx.x;
    if (i < 128) flags[i * FSTR] = -1;
}

// ---------------- cast weights to f16 + bias sums ----------------
__global__ void k_prep_w(const float* __restrict__ whh0, const float* __restrict__ wih1,
                         const float* __restrict__ whh1, const float* __restrict__ wout,
                         const float* __restrict__ bih0, const float* __restrict__ bhh0,
                         const float* __restrict__ bih1, const float* __restrict__ bhh1,
                         _Float16* __restrict__ o0, _Float16* __restrict__ o1,
                         _Float16* __restrict__ o2, _Float16* __restrict__ o3,
                         float* __restrict__ b0s, float* __restrict__ b1s) {
    const int NW = H_ * H_;
    const int total = 3 * NW + DOUT * H_ + 2 * H_;
    int i  = blockIdx.x * blockDim.x + threadIdx.x;
    int st = gridDim.x * blockDim.x;
    for (; i < total; i += st) {
        if      (i < NW)            o0[i]          = (_Float16)whh0[i];
        else if (i < 2 * NW)        o1[i - NW]     = (_Float16)wih1[i - NW];
        else if (i < 3 * NW)        o2[i - 2 * NW] = (_Float16)whh1[i - 2 * NW];
        else if (i < 3 * NW + DOUT * H_) o3[i - 3 * NW] = (_Float16)wout[i - 3 * NW];
        else if (i < 3 * NW + DOUT * H_ + H_) {
            int j = i - (3 * NW + DOUT * H_);
            b0s[j] = bih0[j] + bhh0[j];
        } else {
            int j = i - (3 * NW + DOUT * H_ + H_);
            b1s[j] = bih1[j] + bhh1[j];
        }
    }
}

// ---------------- wcomb[g][d] = sum_h W_ih0[g][h] * W_in[h][d] (proj_in folded in) ----------------
__global__ void k_wcomb(const float* __restrict__ wih0, const float* __restrict__ win,
                        _Float16* __restrict__ o) {
    int g = blockIdx.x;    // 512
    int d = threadIdx.x;   // 64
    float acc = 0.f;
    for (int h = 0; h < H_; ++h)
        acc += wih0[g * H_ + h] * win[h * DIN + d];
    o[g * DIN + d] = (_Float16)acc;
}

// ---------------- helpers ----------------
__device__ __forceinline__ void spin_acq(const int* fp, int tgt) {
    int it = 0;
    while (__hip_atomic_load(fp, __ATOMIC_ACQUIRE, __HIP_MEMORY_SCOPE_AGENT) < tgt) {
        __builtin_amdgcn_s_sleep(1);
        if (++it > SLEEP_CAP) break;
    }
}

__device__ __forceinline__ float tanh_fast(float v) {
    float e = __expf(2.f * v);
    return 1.f - 2.f / (e + 1.f);   // large |v| saturates correctly to +/-1
}

// ---------------- fused persistent pipeline ----------------
// grid = 104 blocks: g = bid&7, role = bid>>3.
//   role 0..3  : L0  (layer-0 recurrence + on-the-fly xw0), col slice 128*role
//   role 4..11 : L1  (layer-1 recurrence + on-the-fly xw1), col slice 64*(role-4)
//   role 12    : G3  (output projection -> d_out)
// h exchanged via depth-4 slot buffers hx0/hx1 [8][4][16][512] f16.
// flags: [0,32) L0, [32,96) L1, [96,104) G3; value = last completed step.
__global__ __launch_bounds__(256, 1)
void k_pipeline(const float* __restrict__ u,
                const _Float16* __restrict__ wcomb,   // [512][64]
                const _Float16* __restrict__ whh0w,   // [512][512]
                const float* __restrict__ b0s,
                const _Float16* __restrict__ wih1w,   // [512][512]
                const _Float16* __restrict__ whh1w,   // [512][512]
                const float* __restrict__ b1s,
                const _Float16* __restrict__ woutw,   // [64][512]
                float* __restrict__ out,              // [B_*L_][64]
                _Float16* __restrict__ hx0,
                _Float16* __restrict__ hx1,
                int* __restrict__ flags) {
    const int bid = blockIdx.x;
    const int g = bid & 7, role = bid >> 3;
    const int tid = threadIdx.x;
    const int l = tid & 63, w = tid >> 6;
    const int l15 = l & 15, lg = l >> 4, kofs = lg * 8;
    const int b0 = g * 16;
    _Float16* hx0g = hx0 + (size_t)g * (4 * 16 * H_);
    _Float16* hx1g = hx1 + (size_t)g * (4 * 16 * H_);

    if (role < 4) {
        // ================= L0 =================
        const int s = role;
        const int col0 = s * 128 + w * 32;
        half8 whf[2][16], wcf[2][2];
#pragma unroll
        for (int nt = 0; nt < 2; ++nt) {
            const int n = col0 + nt * 16 + l15;
#pragma unroll
            for (int kt = 0; kt < 16; ++kt)
                whf[nt][kt] = *(const half8*)(whh0w + (size_t)n * H_ + kt * 32 + kofs);
#pragma unroll
            for (int kt = 0; kt < 2; ++kt)
                wcf[nt][kt] = *(const half8*)(wcomb + (size_t)n * DIN + kt * 32 + kofs);
        }
        const float bv0 = b0s[col0 + l15], bv1 = b0s[col0 + 16 + l15];
        int* myflag = flags + (g * 4 + s) * FSTR;
        // pollers: tid<4 -> L0 partners (lag 1); tid 4..11 -> L1 consumers (lag 4)
        const int* pollp = (tid < 4)  ? flags + (g * 4 + tid) * FSTR
                         : (tid < 12) ? flags + (32 + g * 8 + (tid - 4)) * FSTR : nullptr;
        const int polld = (tid < 4) ? 1 : 4;

        for (int t = 0; t < L_; ++t) {
            // u fragment: independent of sync -> issue first
            const float* up = u + ((size_t)(b0 + l15) * L_ + t) * DIN + kofs;
            f32x4 u0a = *(const f32x4*)(up);
            f32x4 u0b = *(const f32x4*)(up + 4);
            f32x4 u1a = *(const f32x4*)(up + 32);
            f32x4 u1b = *(const f32x4*)(up + 36);
            half8 ua[2];
#pragma unroll
            for (int j = 0; j < 4; ++j) {
                ua[0][j] = (_Float16)u0a[j]; ua[0][4 + j] = (_Float16)u0b[j];
                ua[1][j] = (_Float16)u1a[j]; ua[1][4 + j] = (_Float16)u1b[j];
            }
            if (pollp) spin_acq(pollp, t - polld);
            __syncthreads();
            f32x4 acc0 = (f32x4){bv0, bv0, bv0, bv0};
            f32x4 acc1 = (f32x4){bv1, bv1, bv1, bv1};
#pragma unroll
            for (int kt = 0; kt < 2; ++kt) {
                acc0 = __builtin_amdgcn_mfma_f32_16x16x32_f16(ua[kt], wcf[0][kt], acc0, 0, 0, 0);
                acc1 = __builtin_amdgcn_mfma_f32_16x16x32_f16(ua[kt], wcf[1][kt], acc1, 0, 0, 0);
            }
            if (t > 0) {
                const _Float16* hp = hx0g + (size_t)((t - 1) & 3) * (16 * H_)
                                   + (size_t)l15 * H_ + kofs;
#pragma unroll
                for (int kt = 0; kt < 16; ++kt) {
                    half8 ha = *(const half8*)(hp + kt * 32);
                    acc0 = __builtin_amdgcn_mfma_f32_16x16x32_f16(ha, whf[0][kt], acc0, 0, 0, 0);
                    acc1 = __builtin_amdgcn_mfma_f32_16x16x32_f16(ha, whf[1][kt], acc1, 0, 0, 0);
                }
            }
            _Float16* hq = hx0g + (size_t)(t & 3) * (16 * H_);
#pragma unroll
            for (int r = 0; r < 4; ++r) {
                const int m = lg * 4 + r;
                hq[(size_t)m * H_ + col0 + l15]      = (_Float16)tanh_fast(acc0[r]);
                hq[(size_t)m * H_ + col0 + 16 + l15] = (_Float16)tanh_fast(acc1[r]);
            }
            __syncthreads();
            if (tid == 0) {
                __threadfence();
                __hip_atomic_store(myflag, t, __ATOMIC_RELEASE, __HIP_MEMORY_SCOPE_AGENT);
            }
        }
    } else if (role < 12) {
        // ================= L1 =================
        const int s = role - 4;
        const int col0 = s * 64 + w * 16;
        const int n = col0 + l15;
        half8 wif[16], whf[16];
#pragma unroll
        for (int kt = 0; kt < 16; ++kt) {
            wif[kt] = *(const half8*)(wih1w + (size_t)n * H_ + kt * 32 + kofs);
            whf[kt] = *(const half8*)(whh1w + (size_t)n * H_ + kt * 32 + kofs);
        }
        const float bv = b1s[n];
        int* myflag = flags + (32 + g * 8 + s) * FSTR;
        // pollers: tid<4 -> L0 (lag 0, need h0_t); tid 4..11 -> L1 partners (lag 1);
        //          tid 12 -> G3 (lag 4, hx1 slot reuse)
        const int* pollp = nullptr; int polld = 0;
        if (tid < 4)        { pollp = flags + (g * 4 + tid) * FSTR;            polld = 0; }
        else if (tid < 12)  { pollp = flags + (32 + g * 8 + (tid - 4)) * FSTR; polld = 1; }
        else if (tid == 12) { pollp = flags + (96 + g) * FSTR;                 polld = 4; }

        for (int t = 0; t < L_; ++t) {
            if (pollp) spin_acq(pollp, t - polld);
            __syncthreads();
            f32x4 accx = (f32x4){bv, bv, bv, bv};
            f32x4 acch = (f32x4){0.f, 0.f, 0.f, 0.f};
            const _Float16* h0p = hx0g + (size_t)(t & 3) * (16 * H_)
                                + (size_t)l15 * H_ + kofs;
#pragma unroll
            for (int kt = 0; kt < 16; ++kt) {
                half8 a0 = *(const half8*)(h0p + kt * 32);
                accx = __builtin_amdgcn_mfma_f32_16x16x32_f16(a0, wif[kt], accx, 0, 0, 0);
            }
            if (t > 0) {
                const _Float16* h1p = hx1g + (size_t)((t - 1) & 3) * (16 * H_)
                                    + (size_t)l15 * H_ + kofs;
#pragma unroll
                for (int kt = 0; kt < 16; ++kt) {
                    half8 a1 = *(const half8*)(h1p + kt * 32);
                    acch = __builtin_amdgcn_mfma_f32_16x16x32_f16(a1, whf[kt], acch, 0, 0, 0);
                }
            }
            _Float16* hq = hx1g + (size_t)(t & 3) * (16 * H_);
#pragma unroll
            for (int r = 0; r < 4; ++r)
                hq[(size_t)(lg * 4 + r) * H_ + n] = (_Float16)tanh_fast(accx[r] + acch[r]);
            __syncthreads();
            if (tid == 0) {
                __threadfence();
                __hip_atomic_store(myflag, t, __ATOMIC_RELEASE, __HIP_MEMORY_SCOPE_AGENT);
            }
        }
    } else {
        // ================= G3 (output projection) =================
        const int col0 = w * 16;
        const int n = col0 + l15;
        half8 wof[16];
#pragma unroll
        for (int kt = 0; kt < 16; ++kt)
            wof[kt] = *(const half8*)(woutw + (size_t)n * H_ + kt * 32 + kofs);
        int* myflag = flags + (96 + g) * FSTR;
        const int* pollp = (tid < 8) ? flags + (32 + g * 8 + tid) * FSTR : nullptr;

        for (int t = 0; t < L_; ++t) {
            if (pollp) spin_acq(pollp, t);
            __syncthreads();
            f32x4 acc = (f32x4){0.f, 0.f, 0.f, 0.f};
            const _Float16* h1p = hx1g + (size_t)(t & 3) * (16 * H_)
                                + (size_t)l15 * H_ + kofs;
#pragma unroll
            for (int kt = 0; kt < 16; ++kt) {
                half8 a = *(const half8*)(h1p + kt * 32);
                acc = __builtin_amdgcn_mfma_f32_16x16x32_f16(a, wof[kt], acc, 0, 0, 0);
            }
#pragma unroll
            for (int r = 0; r < 4; ++r)
                out[((size_t)(b0 + lg * 4 + r) * L_ + t) * DOUT + n] = acc[r];
            __syncthreads();   // all h1 reads consumed before signaling slot free
            if (tid == 0) {
                __threadfence();
                __hip_atomic_store(myflag, t, __ATOMIC_RELEASE, __HIP_MEMORY_SCOPE_AGENT);
            }
        }
    }
}

// ---------------- launch ----------------
extern "C" void kernel_launch(void* const* d_in, const int* in_sizes, int n_in,
                              void* d_out, int out_size, void* d_ws, size_t ws_size,
                              hipStream_t stream) {
    const float* u    = (const float*)d_in[0];
    const float* Win  = (const float*)d_in[1];
    const float* Wih0 = (const float*)d_in[2];
    const float* Whh0 = (const float*)d_in[3];
    const float* bih0 = (const float*)d_in[4];
    const float* bhh0 = (const float*)d_in[5];
    const float* Wih1 = (const float*)d_in[6];
    const float* Whh1 = (const float*)d_in[7];
    const float* bih1 = (const float*)d_in[8];
    const float* bhh1 = (const float*)d_in[9];
    const float* Wout = (const float*)d_in[10];
    (void)in_sizes; (void)n_in; (void)out_size; (void)ws_size;

    char* ws = (char*)d_ws;
    size_t off = 0;
    auto alloc = [&](size_t bytes) {
        char* p = ws + off;
        off += (bytes + 255) & ~(size_t)255;
        return p;
    };
    // total workspace: ~2.7 MB
    _Float16* wcomb = (_Float16*)alloc((size_t)H_ * DIN * 2);
    _Float16* whh0h = (_Float16*)alloc((size_t)H_ * H_ * 2);
    _Float16* wih1h = (_Float16*)alloc((size_t)H_ * H_ * 2);
    _Float16* whh1h = (_Float16*)alloc((size_t)H_ * H_ * 2);
    _Float16* wouth = (_Float16*)alloc((size_t)DOUT * H_ * 2);
    float*    b0s   = (float*)alloc(H_ * 4);
    float*    b1s   = (float*)alloc(H_ * 4);
    _Float16* hx0   = (_Float16*)alloc((size_t)8 * 4 * 16 * H_ * 2);
    _Float16* hx1   = (_Float16*)alloc((size_t)8 * 4 * 16 * H_ * 2);
    int*      flags = (int*)alloc(128 * FSTR * 4);

    k_init_flags<<<1, 128, 0, stream>>>(flags);
    k_prep_w<<<1024, 256, 0, stream>>>(Whh0, Wih1, Whh1, Wout, bih0, bhh0, bih1, bhh1,
                                       whh0h, wih1h, whh1h, wouth, b0s, b1s);
    k_wcomb<<<512, 64, 0, stream>>>(Wih0, Win, wcomb);

    k_pipeline<<<104, 256, 0, stream>>>(u, wcomb, whh0h, b0s, wih1h, whh1h, b1s, wouth,
                                        (float*)d_out, hx0, hx1, flags);
}

// Round 3
// 8299.860 us; speedup vs baseline: 1.1307x; 1.1307x over previous
//
#include <hip/hip_runtime.h>
#include <hip/hip_fp16.h>

#define B_   128
#define L_   1024
#define DIN  64
#define H_   512
#define DOUT 64

typedef _Float16 half8 __attribute__((ext_vector_type(8)));
typedef float    f32x4 __attribute__((ext_vector_type(4)));

#define FSTR 16           // flag stride in ints (64B)
#define SLEEP_CAP 65536   // safety: converts a protocol bug into wrong-answer, not a hang

// ---------------- flag init (re-run every launch -> graph-replay safe) ----------------
__global__ void k_init_flags(int* flags) {
    int i = threadIdx.x;
    if (i < 128) flags[i * FSTR] = -1;
}

// ---------------- cast weights to f16 + bias sums ----------------
__global__ void k_prep_w(const float* __restrict__ whh0, const float* __restrict__ wih1,
                         const float* __restrict__ whh1, const float* __restrict__ wout,
                         const float* __restrict__ bih0, const float* __restrict__ bhh0,
                         const float* __restrict__ bih1, const float* __restrict__ bhh1,
                         _Float16* __restrict__ o0, _Float16* __restrict__ o1,
                         _Float16* __restrict__ o2, _Float16* __restrict__ o3,
                         float* __restrict__ b0s, float* __restrict__ b1s) {
    const int NW = H_ * H_;
    const int total = 3 * NW + DOUT * H_ + 2 * H_;
    int i  = blockIdx.x * blockDim.x + threadIdx.x;
    int st = gridDim.x * blockDim.x;
    for (; i < total; i += st) {
        if      (i < NW)            o0[i]          = (_Float16)whh0[i];
        else if (i < 2 * NW)        o1[i - NW]     = (_Float16)wih1[i - NW];
        else if (i < 3 * NW)        o2[i - 2 * NW] = (_Float16)whh1[i - 2 * NW];
        else if (i < 3 * NW + DOUT * H_) o3[i - 3 * NW] = (_Float16)wout[i - 3 * NW];
        else if (i < 3 * NW + DOUT * H_ + H_) {
            int j = i - (3 * NW + DOUT * H_);
            b0s[j] = bih0[j] + bhh0[j];
        } else {
            int j = i - (3 * NW + DOUT * H_ + H_);
            b1s[j] = bih1[j] + bhh1[j];
        }
    }
}

// ---------------- wcomb[g][d] = sum_h W_ih0[g][h] * W_in[h][d] (proj_in folded in) ----------------
__global__ void k_wcomb(const float* __restrict__ wih0, const float* __restrict__ win,
                        _Float16* __restrict__ o) {
    int g = blockIdx.x;    // 512
    int d = threadIdx.x;   // 64
    float acc = 0.f;
    for (int h = 0; h < H_; ++h)
        acc += wih0[g * H_ + h] * win[h * DIN + d];
    o[g * DIN + d] = (_Float16)acc;
}

// ---------------- coherent (L3-point) helpers: sc0 sc1 accesses, NO cache-wide fences ----------------
__device__ __forceinline__ void spin_rel(const int* fp, int tgt) {
    int it = 0;
    while (__hip_atomic_load(fp, __ATOMIC_RELAXED, __HIP_MEMORY_SCOPE_AGENT) < tgt) {
        __builtin_amdgcn_s_sleep(1);
        if (++it > SLEEP_CAP) break;
    }
}

__device__ __forceinline__ uint64_t ld8c(const void* p) {
    return __hip_atomic_load((const uint64_t*)p, __ATOMIC_RELAXED, __HIP_MEMORY_SCOPE_AGENT);
}

__device__ __forceinline__ half8 ldh8c(const _Float16* p) {
    union { uint64_t q[2]; half8 h; } u;
    u.q[0] = ld8c(p);
    u.q[1] = ld8c(p + 4);
    return u.h;
}

__device__ __forceinline__ void st2c(_Float16* p, float v) {
    _Float16 h = (_Float16)v;
    __hip_atomic_store((unsigned short*)p, __builtin_bit_cast(unsigned short, h),
                       __ATOMIC_RELAXED, __HIP_MEMORY_SCOPE_AGENT);
}

__device__ __forceinline__ void flag_pub(int* fp, int t) {
    __hip_atomic_store(fp, t, __ATOMIC_RELAXED, __HIP_MEMORY_SCOPE_AGENT);
}

__device__ __forceinline__ float tanh_fast(float v) {
    float e = __expf(2.f * v);
    return 1.f - 2.f / (e + 1.f);   // large |v| saturates correctly to +/-1
}

// ---------------- fused persistent pipeline ----------------
// grid = 104 blocks: g = bid&7, role = bid>>3.
//   role 0..3  : L0  (layer-0 recurrence + on-the-fly xw0), col slice 128*role
//   role 4..11 : L1  (layer-1 recurrence + on-the-fly xw1), col slice 64*(role-4)
//   role 12    : G3  (output projection -> d_out)
// h exchanged via depth-4 slot buffers hx0/hx1 [8][4][16][512] f16, accessed ONLY with
// agent-scope relaxed atomics (sc0 sc1 -> serviced at L3, no stale L1/L2, no wbl2/inv).
// Ordering: producer drains stores (waitcnt + barrier) before flag publish; consumer's
// data loads are issued only after its flag load returned -> L3 serves fresh data.
__global__ __launch_bounds__(256, 1)
void k_pipeline(const float* __restrict__ u,
                const _Float16* __restrict__ wcomb,   // [512][64]
                const _Float16* __restrict__ whh0w,   // [512][512]
                const float* __restrict__ b0s,
                const _Float16* __restrict__ wih1w,   // [512][512]
                const _Float16* __restrict__ whh1w,   // [512][512]
                const float* __restrict__ b1s,
                const _Float16* __restrict__ woutw,   // [64][512]
                float* __restrict__ out,              // [B_*L_][64]
                _Float16* __restrict__ hx0,
                _Float16* __restrict__ hx1,
                int* __restrict__ flags) {
    const int bid = blockIdx.x;
    const int g = bid & 7, role = bid >> 3;
    const int tid = threadIdx.x;
    const int l = tid & 63, w = tid >> 6;
    const int l15 = l & 15, lg = l >> 4, kofs = lg * 8;
    const int b0 = g * 16;
    _Float16* hx0g = hx0 + (size_t)g * (4 * 16 * H_);
    _Float16* hx1g = hx1 + (size_t)g * (4 * 16 * H_);

    if (role < 4) {
        // ================= L0 =================
        const int s = role;
        const int col0 = s * 128 + w * 32;
        half8 whf[2][16], wcf[2][2];
#pragma unroll
        for (int nt = 0; nt < 2; ++nt) {
            const int n = col0 + nt * 16 + l15;
#pragma unroll
            for (int kt = 0; kt < 16; ++kt)
                whf[nt][kt] = *(const half8*)(whh0w + (size_t)n * H_ + kt * 32 + kofs);
#pragma unroll
            for (int kt = 0; kt < 2; ++kt)
                wcf[nt][kt] = *(const half8*)(wcomb + (size_t)n * DIN + kt * 32 + kofs);
        }
        const float bv0 = b0s[col0 + l15], bv1 = b0s[col0 + 16 + l15];
        int* myflag = flags + (g * 4 + s) * FSTR;
        // pollers: tid<4 -> L0 partners (lag 1); tid 4..11 -> L1 consumers (lag 4)
        const int* pollp = (tid < 4)  ? flags + (g * 4 + tid) * FSTR
                         : (tid < 12) ? flags + (32 + g * 8 + (tid - 4)) * FSTR : nullptr;
        const int polld = (tid < 4) ? 1 : 4;

        for (int t = 0; t < L_; ++t) {
            // u fragment: independent of sync -> issue first (normal cached loads)
            const float* up = u + ((size_t)(b0 + l15) * L_ + t) * DIN + kofs;
            f32x4 u0a = *(const f32x4*)(up);
            f32x4 u0b = *(const f32x4*)(up + 4);
            f32x4 u1a = *(const f32x4*)(up + 32);
            f32x4 u1b = *(const f32x4*)(up + 36);
            half8 ua[2];
#pragma unroll
            for (int j = 0; j < 4; ++j) {
                ua[0][j] = (_Float16)u0a[j]; ua[0][4 + j] = (_Float16)u0b[j];
                ua[1][j] = (_Float16)u1a[j]; ua[1][4 + j] = (_Float16)u1b[j];
            }
            if (pollp) spin_rel(pollp, t - polld);
            __syncthreads();
            asm volatile("" ::: "memory");   // pin h-loads below the flag wait
            f32x4 acc0 = (f32x4){bv0, bv0, bv0, bv0};
            f32x4 acc1 = (f32x4){bv1, bv1, bv1, bv1};
#pragma unroll
            for (int kt = 0; kt < 2; ++kt) {
                acc0 = __builtin_amdgcn_mfma_f32_16x16x32_f16(ua[kt], wcf[0][kt], acc0, 0, 0, 0);
                acc1 = __builtin_amdgcn_mfma_f32_16x16x32_f16(ua[kt], wcf[1][kt], acc1, 0, 0, 0);
            }
            if (t > 0) {
                const _Float16* hp = hx0g + (size_t)((t - 1) & 3) * (16 * H_)
                                   + (size_t)l15 * H_ + kofs;
#pragma unroll
                for (int kt = 0; kt < 16; ++kt) {
                    half8 ha = ldh8c(hp + kt * 32);
                    acc0 = __builtin_amdgcn_mfma_f32_16x16x32_f16(ha, whf[0][kt], acc0, 0, 0, 0);
                    acc1 = __builtin_amdgcn_mfma_f32_16x16x32_f16(ha, whf[1][kt], acc1, 0, 0, 0);
                }
            }
            _Float16* hq = hx0g + (size_t)(t & 3) * (16 * H_);
#pragma unroll
            for (int r = 0; r < 4; ++r) {
                const int m = lg * 4 + r;
                st2c(&hq[(size_t)m * H_ + col0 + l15],      tanh_fast(acc0[r]));
                st2c(&hq[(size_t)m * H_ + col0 + 16 + l15], tanh_fast(acc1[r]));
            }
            asm volatile("s_waitcnt vmcnt(0)" ::: "memory");  // own stores at L3
            __syncthreads();                                  // all waves drained
            if (tid == 0) flag_pub(myflag, t);
        }
    } else if (role < 12) {
        // ================= L1 =================
        const int s = role - 4;
        const int col0 = s * 64 + w * 16;
        const int n = col0 + l15;
        half8 wif[16], whf[16];
#pragma unroll
        for (int kt = 0; kt < 16; ++kt) {
            wif[kt] = *(const half8*)(wih1w + (size_t)n * H_ + kt * 32 + kofs);
            whf[kt] = *(const half8*)(whh1w + (size_t)n * H_ + kt * 32 + kofs);
        }
        const float bv = b1s[n];
        int* myflag = flags + (32 + g * 8 + s) * FSTR;
        // pollers: tid<4 -> L0 (lag 0, need h0_t); tid 4..11 -> L1 partners (lag 1);
        //          tid 12 -> G3 (lag 4, hx1 slot reuse)
        const int* pollp = nullptr; int polld = 0;
        if (tid < 4)        { pollp = flags + (g * 4 + tid) * FSTR;            polld = 0; }
        else if (tid < 12)  { pollp = flags + (32 + g * 8 + (tid - 4)) * FSTR; polld = 1; }
        else if (tid == 12) { pollp = flags + (96 + g) * FSTR;                 polld = 4; }

        for (int t = 0; t < L_; ++t) {
            if (pollp) spin_rel(pollp, t - polld);
            __syncthreads();
            asm volatile("" ::: "memory");
            f32x4 accx = (f32x4){bv, bv, bv, bv};
            f32x4 acch = (f32x4){0.f, 0.f, 0.f, 0.f};
            const _Float16* h0p = hx0g + (size_t)(t & 3) * (16 * H_)
                                + (size_t)l15 * H_ + kofs;
#pragma unroll
            for (int kt = 0; kt < 16; ++kt) {
                half8 a0 = ldh8c(h0p + kt * 32);
                accx = __builtin_amdgcn_mfma_f32_16x16x32_f16(a0, wif[kt], accx, 0, 0, 0);
            }
            if (t > 0) {
                const _Float16* h1p = hx1g + (size_t)((t - 1) & 3) * (16 * H_)
                                    + (size_t)l15 * H_ + kofs;
#pragma unroll
                for (int kt = 0; kt < 16; ++kt) {
                    half8 a1 = ldh8c(h1p + kt * 32);
                    acch = __builtin_amdgcn_mfma_f32_16x16x32_f16(a1, whf[kt], acch, 0, 0, 0);
                }
            }
            _Float16* hq = hx1g + (size_t)(t & 3) * (16 * H_);
#pragma unroll
            for (int r = 0; r < 4; ++r)
                st2c(&hq[(size_t)(lg * 4 + r) * H_ + n], tanh_fast(accx[r] + acch[r]));
            asm volatile("s_waitcnt vmcnt(0)" ::: "memory");
            __syncthreads();
            if (tid == 0) flag_pub(myflag, t);
        }
    } else {
        // ================= G3 (output projection) =================
        const int col0 = w * 16;
        const int n = col0 + l15;
        half8 wof[16];
#pragma unroll
        for (int kt = 0; kt < 16; ++kt)
            wof[kt] = *(const half8*)(woutw + (size_t)n * H_ + kt * 32 + kofs);
        int* myflag = flags + (96 + g) * FSTR;
        const int* pollp = (tid < 8) ? flags + (32 + g * 8 + tid) * FSTR : nullptr;

        for (int t = 0; t < L_; ++t) {
            if (pollp) spin_rel(pollp, t);
            __syncthreads();
            asm volatile("" ::: "memory");
            f32x4 acc = (f32x4){0.f, 0.f, 0.f, 0.f};
            const _Float16* h1p = hx1g + (size_t)(t & 3) * (16 * H_)
                                + (size_t)l15 * H_ + kofs;
#pragma unroll
            for (int kt = 0; kt < 16; ++kt) {
                half8 a = ldh8c(h1p + kt * 32);
                acc = __builtin_amdgcn_mfma_f32_16x16x32_f16(a, wof[kt], acc, 0, 0, 0);
            }
#pragma unroll
            for (int r = 0; r < 4; ++r)
                out[((size_t)(b0 + lg * 4 + r) * L_ + t) * DOUT + n] = acc[r];
            __syncthreads();   // all h1 reads consumed before signaling slot free
            if (tid == 0) flag_pub(myflag, t);
        }
    }
}

// ---------------- launch ----------------
extern "C" void kernel_launch(void* const* d_in, const int* in_sizes, int n_in,
                              void* d_out, int out_size, void* d_ws, size_t ws_size,
                              hipStream_t stream) {
    const float* u    = (const float*)d_in[0];
    const float* Win  = (const float*)d_in[1];
    const float* Wih0 = (const float*)d_in[2];
    const float* Whh0 = (const float*)d_in[3];
    const float* bih0 = (const float*)d_in[4];
    const float* bhh0 = (const float*)d_in[5];
    const float* Wih1 = (const float*)d_in[6];
    const float* Whh1 = (const float*)d_in[7];
    const float* bih1 = (const float*)d_in[8];
    const float* bhh1 = (const float*)d_in[9];
    const float* Wout = (const float*)d_in[10];
    (void)in_sizes; (void)n_in; (void)out_size; (void)ws_size;

    char* ws = (char*)d_ws;
    size_t off = 0;
    auto alloc = [&](size_t bytes) {
        char* p = ws + off;
        off += (bytes + 255) & ~(size_t)255;
        return p;
    };
    // total workspace: ~2.7 MB
    _Float16* wcomb = (_Float16*)alloc((size_t)H_ * DIN * 2);
    _Float16* whh0h = (_Float16*)alloc((size_t)H_ * H_ * 2);
    _Float16* wih1h = (_Float16*)alloc((size_t)H_ * H_ * 2);
    _Float16* whh1h = (_Float16*)alloc((size_t)H_ * H_ * 2);
    _Float16* wouth = (_Float16*)alloc((size_t)DOUT * H_ * 2);
    float*    b0s   = (float*)alloc(H_ * 4);
    float*    b1s   = (float*)alloc(H_ * 4);
    _Float16* hx0   = (_Float16*)alloc((size_t)8 * 4 * 16 * H_ * 2);
    _Float16* hx1   = (_Float16*)alloc((size_t)8 * 4 * 16 * H_ * 2);
    int*      flags = (int*)alloc(128 * FSTR * 4);

    k_init_flags<<<1, 128, 0, stream>>>(flags);
    k_prep_w<<<1024, 256, 0, stream>>>(Whh0, Wih1, Whh1, Wout, bih0, bhh0, bih1, bhh1,
                                       whh0h, wih1h, whh1h, wouth, b0s, b1s);
    k_wcomb<<<512, 64, 0, stream>>>(Wih0, Win, wcomb);

    k_pipeline<<<104, 256, 0, stream>>>(u, wcomb, whh0h, b0s, wih1h, whh1h, b1s, wouth,
                                        (float*)d_out, hx0, hx1, flags);
}